// Round 8
// baseline (404.132 us; speedup 1.0000x reference)
//
#include <hip/hip_runtime.h>
#include <stdint.h>

#define N_NODES 100000
#define N_EDGES 1600000
#define F 128
#define CBN 512                    // nodes per coarse bucket
#define NCBK 196                   // ceil(N_NODES/CBN)
#define CHUNK 4096                 // edges per binA block
#define BUFCAP 10240               // per-bucket region cap (mean 8163 + ~23 sigma)

typedef _Float16 f16;
typedef _Float16 f16x4 __attribute__((ext_vector_type(4)));
typedef _Float16 f16x8 __attribute__((ext_vector_type(8)));
typedef float f32x4 __attribute__((ext_vector_type(4)));

// edge pack: (src << 15) | (fp16 bits of w, sign bit dropped — w in [0,1))
__device__ inline float unpackw(unsigned int p) {
    unsigned short b = (unsigned short)(p & 0x7FFF);
    return (float)__builtin_bit_cast(f16, b);
}

// wave-local LDS fence: same-wave cross-lane LDS handoff without a block barrier
__device__ inline void lds_fence_wave() {
    asm volatile("s_waitcnt lgkmcnt(0)" ::: "memory");
    __builtin_amdgcn_sched_barrier(0);
}

// ---------------- LDS write-combining binner (R13, proven) ----------------

__launch_bounds__(256)
__global__ void k_binA(const int* __restrict__ ei, const float* __restrict__ w,
                       int* __restrict__ gcur, int2* __restrict__ stage, int e) {
    __shared__ int hist[256];
    __shared__ int bst[257];
    __shared__ int gb[256];
    __shared__ int ls[256];
    __shared__ int rec[CHUNK];
    __shared__ int meta[CHUNK];
    int tid = threadIdx.x;
    int base = blockIdx.x * CHUNK;
    int cnt = min(CHUNK, e - base);
    hist[tid] = 0;
    __syncthreads();

    int ew_[16], mr_[16];
    int nloc = 0;
    if (cnt == CHUNK) {
#pragma unroll
        for (int k = 0; k < 16; k++) {
            int i = base + tid + k * 256;
            int s = ei[i];
            int d = ei[N_EDGES + i];
            f16 hw = (f16)w[i];
            unsigned short wb = __builtin_bit_cast(unsigned short, hw);
            ew_[k] = (int)(((unsigned int)s << 15) | (wb & 0x7FFF));
            int cb = d >> 9;
            int local = d & (CBN - 1);
            int r = atomicAdd(&hist[cb], 1);
            mr_[k] = (cb << 22) | (local << 13) | r;   // cb:8 local:9 r:13
        }
        nloc = 16;
    } else {
        for (int i = tid; i < cnt; i += 256) {
            int s = ei[base + i];
            int d = ei[N_EDGES + base + i];
            f16 hw = (f16)w[base + i];
            unsigned short wb = __builtin_bit_cast(unsigned short, hw);
            ew_[nloc] = (int)(((unsigned int)s << 15) | (wb & 0x7FFF));
            int cb = d >> 9;
            int local = d & (CBN - 1);
            int r = atomicAdd(&hist[cb], 1);
            mr_[nloc] = (cb << 22) | (local << 13) | r;
            nloc++;
        }
    }
    __syncthreads();
    int v = hist[tid];
    ls[tid] = v;
    __syncthreads();
    for (int off = 1; off < 256; off <<= 1) {
        int t = (tid >= off) ? ls[tid - off] : 0;
        __syncthreads();
        ls[tid] += t;
        __syncthreads();
    }
    bst[tid] = ls[tid] - v;
    if (tid == 255) bst[256] = ls[255];
    __syncthreads();
    for (int k = 0; k < nloc; k++) {
        int m = mr_[k];
        int cb = m >> 22;
        int pos = bst[cb] + (m & 0x1FFF);
        rec[pos] = ew_[k];
        meta[pos] = (cb << 9) | ((m >> 13) & 0x1FF);
    }
    __syncthreads();
    if (tid < NCBK) {
        int c = bst[tid + 1] - bst[tid];
        gb[tid] = c ? atomicAdd(&gcur[tid], c) : 0;
    }
    __syncthreads();
    for (int j = tid; j < cnt; j += 256) {
        int m = meta[j];
        int cb = m >> 9;
        stage[(size_t)cb * BUFCAP + gb[cb] + (j - bst[cb])] = make_int2(m & 511, rec[j]);
    }
}

// binB: one block per coarse bucket. pass1 count locals -> LDS scan -> row2
// write; pass2 permute to CSR order in LDS; coalesced final write + fused dinv.
__launch_bounds__(256)
__global__ void k_binB(const int2* __restrict__ stage, const int* __restrict__ gcur,
                       unsigned int* __restrict__ edges, int2* __restrict__ row2,
                       float* __restrict__ dinv) {
    __shared__ int cnt[CBN];
    __shared__ int ex[CBN + 1];
    __shared__ int cur[CBN];
    __shared__ int ls[256];
    __shared__ unsigned int buf[BUFCAP];
    int tid = threadIdx.x;
    int cb = blockIdx.x;
    int n0 = cb * CBN;
    int nn = min(CBN, N_NODES - n0);
    size_t sbase = (size_t)cb * BUFCAP;
    int ecnt = gcur[cb];
    cnt[tid] = 0;
    cnt[tid + 256] = 0;
    __syncthreads();
    // pass 1: local histogram
    for (int j = tid; j < ecnt; j += 256)
        atomicAdd(&cnt[stage[sbase + j].x], 1);
    __syncthreads();
    // exclusive scan of 512 (2 per thread)
    int a = cnt[2 * tid], b = cnt[2 * tid + 1];
    int s = a + b;
    ls[tid] = s;
    __syncthreads();
    for (int off = 1; off < 256; off <<= 1) {
        int t = (tid >= off) ? ls[tid - off] : 0;
        __syncthreads();
        ls[tid] += t;
        __syncthreads();
    }
    int bx = ls[tid] - s;
    ex[2 * tid] = bx;
    ex[2 * tid + 1] = bx + a;
    cur[2 * tid] = bx;
    cur[2 * tid + 1] = bx + a;
    if (tid == 255) ex[512] = ls[255];
    __syncthreads();
    // per-node (beg,end) pairs — padding gaps between buckets are harmless
    for (int l = tid; l < nn; l += 256)
        row2[n0 + l] = make_int2((int)sbase + ex[l], (int)sbase + ex[l + 1]);
    // pass 2: permute to CSR order in LDS
    for (int j = tid; j < ecnt; j += 256) {
        int2 r = stage[sbase + j];
        int p = atomicAdd(&cur[r.x], 1);
        buf[p] = (unsigned int)r.y;
    }
    __syncthreads();
    for (int j = tid; j < ecnt; j += 256)
        edges[sbase + j] = buf[j];
    // fused dinv: deg = 1 + sum w over the node's CSR slice (in LDS)
    for (int l = tid; l < nn; l += 256) {
        int lo = ex[l];
        int h2 = ex[l + 1];
        float sm = 1.0f;
        for (int j = lo; j < h2; j++) sm += unpackw(buf[j]);
        dinv[n0 + l] = rsqrtf(sm);
    }
}

// ---------------- weight transpose + front-end init (fused) ----------------

__global__ void k_wt2(const float* __restrict__ Wa, const float* __restrict__ Wb,
                      f16* __restrict__ Wta, f16* __restrict__ Wtb,
                      int* __restrict__ gcur, unsigned int* __restrict__ edges) {
    int t = threadIdx.x;
    if (blockIdx.x == 2) {
        if (t < NCBK) gcur[t] = 0;
        // 8 zero sentinels past the last bucket region (uint4 tail overread)
        if (t >= 248) edges[(size_t)NCBK * BUFCAP + (t - 248)] = 0u;
        return;
    }
    const float* W = blockIdx.x ? Wb : Wa;
    f16* Wt = blockIdx.x ? Wtb : Wta;
#pragma unroll
    for (int it = 0; it < 64; it++) {
        int idx = t + it * 256;            // output index (n*128+k), coalesced
        int n = idx >> 7, k = idx & 127;
        Wt[idx] = (f16)W[k * 128 + n];
    }
}

#define LDK 136

// ---------------- GEMM layer 1 (R21: single barrier, Ws in LDS, fused cvt) ----------------

__launch_bounds__(256, 2)
__global__ void k_gemmf(const float* __restrict__ A, const f16* __restrict__ Wt,
                        const float* __restrict__ dinv, f16* __restrict__ H, int nrows) {
    __shared__ f16 S[128 * LDK];           // per-wave epilogue regions
    __shared__ f16 Ws[128 * LDK];          // staged Wt (padded: conflict-free B reads)
    int tid = threadIdx.x;
    int r0 = blockIdx.x * 128;
    int wave = tid >> 6;
    int lane = tid & 63;
    int sub = lane & 15;
    int quad = lane >> 4;

    // stage Ws (published by the single barrier below)
#pragma unroll
    for (int it = 0; it < 8; it++) {
        int c = tid + it * 256;
        int rw = c >> 4;
        int off = (c & 15) * 8;
        *(f16x8*)&Ws[rw * LDK + off] = *(const f16x8*)&Wt[rw * 128 + off];
    }

    f16x8 a[2][4];
#pragma unroll
    for (int mt = 0; mt < 2; mt++) {
        int row = r0 + wave * 32 + mt * 16 + sub;
#pragma unroll
        for (int kc = 0; kc < 4; kc++) {
            if (row < nrows) {
                float4 lo = *(const float4*)&A[(size_t)row * F + kc * 32 + quad * 8];
                float4 hi = *(const float4*)&A[(size_t)row * F + kc * 32 + quad * 8 + 4];
                f16x8 f;
                f[0] = (f16)lo.x; f[1] = (f16)lo.y; f[2] = (f16)lo.z; f[3] = (f16)lo.w;
                f[4] = (f16)hi.x; f[5] = (f16)hi.y; f[6] = (f16)hi.z; f[7] = (f16)hi.w;
                a[mt][kc] = f;
            } else {
                a[mt][kc] = (f16x8){};
            }
        }
    }
    __syncthreads();   // Ws ready

    f32x4 acc[2][8] = {};
#pragma unroll
    for (int kc = 0; kc < 4; kc++) {
        f16x8 b[8];
#pragma unroll
        for (int nt = 0; nt < 8; nt++)
            b[nt] = *(const f16x8*)&Ws[(nt * 16 + sub) * LDK + kc * 32 + quad * 8];
#pragma unroll
        for (int nt = 0; nt < 8; nt++) {
            acc[0][nt] = __builtin_amdgcn_mfma_f32_16x16x32_f16(a[0][kc], b[nt], acc[0][nt], 0, 0, 0);
            acc[1][nt] = __builtin_amdgcn_mfma_f32_16x16x32_f16(a[1][kc], b[nt], acc[1][nt], 0, 0, 0);
        }
    }
    // per-wave epilogue (own 32 rows, stride LDK — no cross-wave aliasing)
#pragma unroll
    for (int mt = 0; mt < 2; mt++) {
#pragma unroll
        for (int r = 0; r < 4; r++) {
            int lr = wave * 32 + mt * 16 + quad * 4 + r;
            int grow = r0 + lr;
            float dv = (grow < nrows) ? dinv[grow] : 0.f;
#pragma unroll
            for (int nt = 0; nt < 8; nt++)
                S[lr * LDK + nt * 16 + sub] = (f16)(acc[mt][nt][r] * dv);
        }
    }
    lds_fence_wave();
#pragma unroll
    for (int it = 0; it < 8; it++) {
        int lr = wave * 32 + it * 4 + quad;
        int grow = r0 + lr;
        if (grow < nrows)
            *(f16x8*)&H[(size_t)grow * F + sub * 8] = *(const f16x8*)&S[lr * LDK + sub * 8];
    }
}

// ---------------- R21: fused aggregation + GEMM, single barrier ----------------
// Ws (Wt) staged into a separate padded LDS buffer BEFORE the gather; the
// A-tile S is wave-private (each wave writes/reads only its own 32 rows). The
// ONE __syncthreads after the gather publishes Ws; everything else is
// wave-local -> a wave that finishes its gather proceeds straight into MFMA
// while sibling waves still gather (B stays in LDS: no extra VMEM queue
// pressure — the R20 mistake).
__launch_bounds__(256, 2)
__global__ void k_agg_gemm(const f16* __restrict__ Hin, const int2* __restrict__ row2,
                           const unsigned int* __restrict__ edges,
                           const float* __restrict__ dinv, const float* __restrict__ bias,
                           const f16* __restrict__ Wt, f16* __restrict__ Hout, int nrows) {
    __shared__ f16 S[128 * LDK];
    __shared__ f16 Ws[128 * LDK];
    int tid = threadIdx.x;
    int r0 = blockIdx.x * 128;
    int wave = tid >> 6;
    int lane = tid & 63;
    int sub = lane & 15;
    int quad = lane >> 4;

    // stage Ws first (completes under the gather; published by the one barrier)
#pragma unroll
    for (int it = 0; it < 8; it++) {
        int c = tid + it * 256;
        int rw = c >> 4;
        int off = (c & 15) * 8;
        *(f16x8*)&Ws[rw * LDK + off] = *(const f16x8*)&Wt[rw * 128 + off];
    }

    // ---- phase 1: this wave aggregates its 32 rows into S ----
    float4 b0 = *(const float4*)&bias[sub * 8];
    float4 b1 = *(const float4*)&bias[sub * 8 + 4];
    float bb[8] = {b0.x, b0.y, b0.z, b0.w, b1.x, b1.y, b1.z, b1.w};
    for (int it = 0; it < 8; it++) {
        int l = wave * 32 + it * 4 + quad;     // own row 0..127
        int node = r0 + l;
        f16x8 o = (f16x8){};
        if (node < nrows) {
            int2 rr = row2[node];
            int beg = rr.x, end = rr.y;
            float acc0[8] = {}, acc1[8] = {}, acc2[8] = {}, acc3[8] = {};
            for (int t = (beg & ~3); t < end; t += 8) {
                uint4 ea = *(const uint4*)&edges[t];
                uint4 eb = *(const uint4*)&edges[t + 4];
                unsigned int e[8] = {ea.x, ea.y, ea.z, ea.w, eb.x, eb.y, eb.z, eb.w};
                float w[8];
                unsigned int srcw[8];
#pragma unroll
                for (int k = 0; k < 8; k++) {
                    bool live = (t + k >= beg) && (t + k < end);
                    w[k] = live ? unpackw(e[k]) : 0.f;
                    srcw[k] = (t + k < end) ? e[k] : ea.x;
                }
                f16x8 v[8];
#pragma unroll
                for (int k = 0; k < 8; k++)
                    v[k] = *(const f16x8*)&Hin[(size_t)(srcw[k] >> 15) * F + sub * 8];
#pragma unroll
                for (int j = 0; j < 8; j++) {
                    acc0[j] = fmaf(w[0], (float)v[0][j], acc0[j]);
                    acc1[j] = fmaf(w[1], (float)v[1][j], acc1[j]);
                    acc2[j] = fmaf(w[2], (float)v[2][j], acc2[j]);
                    acc3[j] = fmaf(w[3], (float)v[3][j], acc3[j]);
                    acc0[j] = fmaf(w[4], (float)v[4][j], acc0[j]);
                    acc1[j] = fmaf(w[5], (float)v[5][j], acc1[j]);
                    acc2[j] = fmaf(w[6], (float)v[6][j], acc2[j]);
                    acc3[j] = fmaf(w[7], (float)v[7][j], acc3[j]);
                }
            }
            float dd = dinv[node];
            f16x8 h = *(const f16x8*)&Hin[(size_t)node * F + sub * 8];
#pragma unroll
            for (int j = 0; j < 8; j++) {
                float a = acc0[j] + acc1[j] + acc2[j] + acc3[j] + (float)h[j];
                o[j] = (f16)fmaxf(fmaf(dd, a, bb[j]), 0.f);
            }
        }
        *(f16x8*)&S[l * LDK + sub * 8] = o;
    }
    __syncthreads();   // publishes Ws (and covers own-S writes)

    // ---- phase 2: a-frags from own rows; B from Ws (LDS, padded) ----
    f16x8 a[2][4];
#pragma unroll
    for (int mt = 0; mt < 2; mt++) {
        int l = wave * 32 + mt * 16 + sub;
#pragma unroll
        for (int kc = 0; kc < 4; kc++)
            a[mt][kc] = *(const f16x8*)&S[l * LDK + kc * 32 + quad * 8];
    }

    f32x4 acc[2][8] = {};
#pragma unroll
    for (int kc = 0; kc < 4; kc++) {
        f16x8 b[8];
#pragma unroll
        for (int nt = 0; nt < 8; nt++)
            b[nt] = *(const f16x8*)&Ws[(nt * 16 + sub) * LDK + kc * 32 + quad * 8];
#pragma unroll
        for (int nt = 0; nt < 8; nt++) {
            acc[0][nt] = __builtin_amdgcn_mfma_f32_16x16x32_f16(a[0][kc], b[nt], acc[0][nt], 0, 0, 0);
            acc[1][nt] = __builtin_amdgcn_mfma_f32_16x16x32_f16(a[1][kc], b[nt], acc[1][nt], 0, 0, 0);
        }
    }
    // per-wave epilogue (own rows, stride LDK; a-frags already consumed)
#pragma unroll
    for (int mt = 0; mt < 2; mt++) {
#pragma unroll
        for (int r = 0; r < 4; r++) {
            int lr = wave * 32 + mt * 16 + quad * 4 + r;
            int grow = r0 + lr;
            float dv = (grow < nrows) ? dinv[grow] : 0.f;
#pragma unroll
            for (int nt = 0; nt < 8; nt++)
                S[lr * LDK + nt * 16 + sub] = (f16)(acc[mt][nt][r] * dv);
        }
    }
    lds_fence_wave();
#pragma unroll
    for (int it = 0; it < 8; it++) {
        int lr = wave * 32 + it * 4 + quad;
        int grow = r0 + lr;
        if (grow < nrows)
            *(f16x8*)&Hout[(size_t)grow * F + sub * 8] = *(const f16x8*)&S[lr * LDK + sub * 8];
    }
}

// agg3 fused with final dot: s'[node] = dinv[node] * ( relu(agg3) . Wfin )
__launch_bounds__(256)
__global__ void k_agg_dot(const f16* __restrict__ H16, const int2* __restrict__ row2,
                          const unsigned int* __restrict__ edges,
                          const float* __restrict__ dinv, const float* __restrict__ bias,
                          const float* __restrict__ Wf, float* __restrict__ sout, int n) {
    int node = blockIdx.x * 16 + (threadIdx.x >> 4);
    if (node >= n) return;
    int sub = threadIdx.x & 15;
    int2 rr = row2[node];
    int beg = rr.x, end = rr.y;
    float acc0[8] = {}, acc1[8] = {}, acc2[8] = {}, acc3[8] = {};
    for (int t = (beg & ~3); t < end; t += 8) {
        uint4 ea = *(const uint4*)&edges[t];
        uint4 eb = *(const uint4*)&edges[t + 4];
        unsigned int e[8] = {ea.x, ea.y, ea.z, ea.w, eb.x, eb.y, eb.z, eb.w};
        float w[8];
        unsigned int srcw[8];
#pragma unroll
        for (int k = 0; k < 8; k++) {
            bool live = (t + k >= beg) && (t + k < end);
            w[k] = live ? unpackw(e[k]) : 0.f;
            srcw[k] = (t + k < end) ? e[k] : ea.x;
        }
        f16x8 v[8];
#pragma unroll
        for (int k = 0; k < 8; k++)
            v[k] = *(const f16x8*)&H16[(size_t)(srcw[k] >> 15) * F + sub * 8];
#pragma unroll
        for (int j = 0; j < 8; j++) {
            acc0[j] = fmaf(w[0], (float)v[0][j], acc0[j]);
            acc1[j] = fmaf(w[1], (float)v[1][j], acc1[j]);
            acc2[j] = fmaf(w[2], (float)v[2][j], acc2[j]);
            acc3[j] = fmaf(w[3], (float)v[3][j], acc3[j]);
            acc0[j] = fmaf(w[4], (float)v[4][j], acc0[j]);
            acc1[j] = fmaf(w[5], (float)v[5][j], acc1[j]);
            acc2[j] = fmaf(w[6], (float)v[6][j], acc2[j]);
            acc3[j] = fmaf(w[7], (float)v[7][j], acc3[j]);
        }
    }
    float dd = dinv[node];
    f16x8 h = *(const f16x8*)&H16[(size_t)node * F + sub * 8];
    float4 b0 = *(const float4*)&bias[sub * 8];
    float4 b1 = *(const float4*)&bias[sub * 8 + 4];
    float bb[8] = {b0.x, b0.y, b0.z, b0.w, b1.x, b1.y, b1.z, b1.w};
    float4 w0v = *(const float4*)&Wf[sub * 8];
    float4 w1v = *(const float4*)&Wf[sub * 8 + 4];
    float ww[8] = {w0v.x, w0v.y, w0v.z, w0v.w, w1v.x, w1v.y, w1v.z, w1v.w};
    float p = 0.f;
#pragma unroll
    for (int j = 0; j < 8; j++) {
        float a = acc0[j] + acc1[j] + acc2[j] + acc3[j] + (float)h[j];
        p += fmaxf(fmaf(dd, a, bb[j]), 0.f) * ww[j];
    }
    p += __shfl_xor(p, 8, 64);
    p += __shfl_xor(p, 4, 64);
    p += __shfl_xor(p, 2, 64);
    p += __shfl_xor(p, 1, 64);
    if (sub == 0) sout[node] = dd * p;
}

__global__ void k_aggs(const float* __restrict__ s, const int2* __restrict__ row2,
                       const unsigned int* __restrict__ edges,
                       const float* __restrict__ dinv, const float* __restrict__ bf,
                       float* __restrict__ out, int n) {
    int i = blockIdx.x * blockDim.x + threadIdx.x;
    if (i >= n) return;
    float dd = dinv[i];
    float ae = s[i];
    int2 rr = row2[i];
    for (int j = rr.x; j < rr.y; j++) {
        unsigned int p = edges[j];
        ae = fmaf(unpackw(p), s[p >> 15], ae);
    }
    out[i] = fmaf(dd, ae, bf[0]);
}

// ---------------- host launch ----------------

extern "C" void kernel_launch(void* const* d_in, const int* in_sizes, int n_in,
                              void* d_out, int out_size, void* d_ws, size_t ws_size,
                              hipStream_t stream) {
    const float* x    = (const float*)d_in[0];
    const int*   ei   = (const int*)d_in[1];
    const float* ew   = (const float*)d_in[2];
    const float* Win  = (const float*)d_in[3];
    const float* bin  = (const float*)d_in[4];
    const float* Wmid = (const float*)d_in[5];
    const float* bmid = (const float*)d_in[6];
    const float* Wfin = (const float*)d_in[7];
    const float* bfin = (const float*)d_in[8];
    float* out = (float*)d_out;

    char* ws = (char*)d_ws;
    size_t off = 0;
    auto alloc = [&](size_t bytes) -> char* {
        char* p = ws + off;
        off = (off + bytes + 255) & ~(size_t)255;
        return p;
    };
    float* dinv  = (float*)alloc((size_t)N_NODES * 4);
    int2*  row2  = (int2*)alloc((size_t)N_NODES * 8);
    unsigned int* edges = (unsigned int*)alloc(((size_t)NCBK * BUFCAP + 8) * 4);  // padded buckets + sentinels
    int*   gcur  = (int*)alloc(256 * 4);
    f16*   wtin  = (f16*)alloc(128 * 128 * 2);
    f16*   wtmid = (f16*)alloc(128 * 128 * 2);
    f16*   Ha    = (f16*)alloc((size_t)N_NODES * F * 2);   // ping
    f16*   Hb    = (f16*)alloc((size_t)N_NODES * F * 2);   // pong
    // stage aliased into Ha (consumed by binB before gemmf writes Ha):
    // NCBK * BUFCAP * 8 B = 16.06 MB <= 25.6 MB
    int2* stage = (int2*)Ha;
    float* sbuf = (float*)Hb;  // aliased: Hb consumed by fused2 before agg_dot writes

    dim3 b256(256);
    int gN = (N_NODES + 255) / 256;
    int gW = (N_NODES + 15) / 16;
    int gG = (N_NODES + 127) / 128;
    int gA = (N_EDGES + CHUNK - 1) / CHUNK;   // 391

    hipLaunchKernelGGL(k_wt2, dim3(3), b256, 0, stream, Win, Wmid, wtin, wtmid, gcur, edges);
    hipLaunchKernelGGL(k_binA, dim3(gA), b256, 0, stream, ei, ew, gcur, stage, N_EDGES);
    hipLaunchKernelGGL(k_binB, dim3(NCBK), b256, 0, stream, stage, gcur, edges, row2, dinv);

    hipLaunchKernelGGL(k_gemmf, dim3(gG), b256, 0, stream, x, wtin, dinv, Ha, N_NODES);
    hipLaunchKernelGGL(k_agg_gemm, dim3(gG), b256, 0, stream, Ha, row2, edges, dinv, bin, wtmid, Hb, N_NODES);
    hipLaunchKernelGGL(k_agg_gemm, dim3(gG), b256, 0, stream, Hb, row2, edges, dinv, bmid, wtmid, Ha, N_NODES);
    hipLaunchKernelGGL(k_agg_dot, dim3(gW), b256, 0, stream, Ha, row2, edges, dinv, bmid, Wfin, sbuf, N_NODES);
    hipLaunchKernelGGL(k_aggs, dim3(gN), b256, 0, stream, sbuf, row2, edges, dinv, bfin, out, N_NODES);
}

// Round 9
// 381.161 us; speedup vs baseline: 1.0603x; 1.0603x over previous
//
#include <hip/hip_runtime.h>
#include <stdint.h>

#define N_NODES 100000
#define N_EDGES 1600000
#define F 128
#define CBN 512                    // nodes per coarse bucket
#define NCBK 196                   // ceil(N_NODES/CBN)
#define CHUNK 4096                 // edges per binA block
#define BUFCAP 10240               // per-bucket region cap (mean 8163 + ~23 sigma)

typedef _Float16 f16;
typedef _Float16 f16x4 __attribute__((ext_vector_type(4)));
typedef _Float16 f16x8 __attribute__((ext_vector_type(8)));
typedef float f32x4 __attribute__((ext_vector_type(4)));

// edge pack: (src << 15) | (fp16 bits of w, sign bit dropped — w in [0,1))
__device__ inline float unpackw(unsigned int p) {
    unsigned short b = (unsigned short)(p & 0x7FFF);
    return (float)__builtin_bit_cast(f16, b);
}

// ---------------- R18 front-end: padded-bucket, no histogram/scan ----------------
// Each bucket cb owns stage[cb*BUFCAP ..] and edges[cb*BUFCAP ..]; binA appends
// via gcur (zero-based), binB compacts within the bucket. CSR is per-node
// (beg,end) pairs (row2) so the inter-bucket padding gaps are harmless.

// ---------------- LDS write-combining binner (R13, proven) ----------------
// Measured R9-R12: scattered/temporally-sparse partial-line writes cost ~5x
// write amplification. binA converts per-edge scatter into per-(block,bin)
// contiguous runs claimed with one atomic each.

__launch_bounds__(256)
__global__ void k_binA(const int* __restrict__ ei, const float* __restrict__ w,
                       int* __restrict__ gcur, int2* __restrict__ stage, int e) {
    __shared__ int hist[256];
    __shared__ int bst[257];
    __shared__ int gb[256];
    __shared__ int ls[256];
    __shared__ int rec[CHUNK];
    __shared__ int meta[CHUNK];
    int tid = threadIdx.x;
    int base = blockIdx.x * CHUNK;
    int cnt = min(CHUNK, e - base);
    hist[tid] = 0;
    __syncthreads();

    int ew_[16], mr_[16];
    int nloc = 0;
    if (cnt == CHUNK) {
#pragma unroll
        for (int k = 0; k < 16; k++) {
            int i = base + tid + k * 256;
            int s = ei[i];
            int d = ei[N_EDGES + i];
            f16 hw = (f16)w[i];
            unsigned short wb = __builtin_bit_cast(unsigned short, hw);
            ew_[k] = (int)(((unsigned int)s << 15) | (wb & 0x7FFF));
            int cb = d >> 9;
            int local = d & (CBN - 1);
            int r = atomicAdd(&hist[cb], 1);
            mr_[k] = (cb << 22) | (local << 13) | r;   // cb:8 local:9 r:13
        }
        nloc = 16;
    } else {
        for (int i = tid; i < cnt; i += 256) {
            int s = ei[base + i];
            int d = ei[N_EDGES + base + i];
            f16 hw = (f16)w[base + i];
            unsigned short wb = __builtin_bit_cast(unsigned short, hw);
            ew_[nloc] = (int)(((unsigned int)s << 15) | (wb & 0x7FFF));
            int cb = d >> 9;
            int local = d & (CBN - 1);
            int r = atomicAdd(&hist[cb], 1);
            mr_[nloc] = (cb << 22) | (local << 13) | r;
            nloc++;
        }
    }
    __syncthreads();
    int v = hist[tid];
    ls[tid] = v;
    __syncthreads();
    for (int off = 1; off < 256; off <<= 1) {
        int t = (tid >= off) ? ls[tid - off] : 0;
        __syncthreads();
        ls[tid] += t;
        __syncthreads();
    }
    bst[tid] = ls[tid] - v;
    if (tid == 255) bst[256] = ls[255];
    __syncthreads();
    for (int k = 0; k < nloc; k++) {
        int m = mr_[k];
        int cb = m >> 22;
        int pos = bst[cb] + (m & 0x1FFF);
        rec[pos] = ew_[k];
        meta[pos] = (cb << 9) | ((m >> 13) & 0x1FF);
    }
    __syncthreads();
    if (tid < NCBK) {
        int c = bst[tid + 1] - bst[tid];
        gb[tid] = c ? atomicAdd(&gcur[tid], c) : 0;
    }
    __syncthreads();
    for (int j = tid; j < cnt; j += 256) {
        int m = meta[j];
        int cb = m >> 9;
        stage[(size_t)cb * BUFCAP + gb[cb] + (j - bst[cb])] = make_int2(m & 511, rec[j]);
    }
}

// binB: one block per coarse bucket. pass1 count locals -> LDS scan -> row2
// write; pass2 permute to CSR order in LDS; coalesced final write + fused dinv.
__launch_bounds__(256)
__global__ void k_binB(const int2* __restrict__ stage, const int* __restrict__ gcur,
                       unsigned int* __restrict__ edges, int2* __restrict__ row2,
                       float* __restrict__ dinv) {
    __shared__ int cnt[CBN];
    __shared__ int ex[CBN + 1];
    __shared__ int cur[CBN];
    __shared__ int ls[256];
    __shared__ unsigned int buf[BUFCAP];
    int tid = threadIdx.x;
    int cb = blockIdx.x;
    int n0 = cb * CBN;
    int nn = min(CBN, N_NODES - n0);
    size_t sbase = (size_t)cb * BUFCAP;
    int ecnt = gcur[cb];
    cnt[tid] = 0;
    cnt[tid + 256] = 0;
    __syncthreads();
    // pass 1: local histogram
    for (int j = tid; j < ecnt; j += 256)
        atomicAdd(&cnt[stage[sbase + j].x], 1);
    __syncthreads();
    // exclusive scan of 512 (2 per thread)
    int a = cnt[2 * tid], b = cnt[2 * tid + 1];
    int s = a + b;
    ls[tid] = s;
    __syncthreads();
    for (int off = 1; off < 256; off <<= 1) {
        int t = (tid >= off) ? ls[tid - off] : 0;
        __syncthreads();
        ls[tid] += t;
        __syncthreads();
    }
    int bx = ls[tid] - s;
    ex[2 * tid] = bx;
    ex[2 * tid + 1] = bx + a;
    cur[2 * tid] = bx;
    cur[2 * tid + 1] = bx + a;
    if (tid == 255) ex[512] = ls[255];
    __syncthreads();
    // per-node (beg,end) pairs — padding gaps between buckets are harmless
    for (int l = tid; l < nn; l += 256)
        row2[n0 + l] = make_int2((int)sbase + ex[l], (int)sbase + ex[l + 1]);
    // pass 2: permute to CSR order in LDS
    for (int j = tid; j < ecnt; j += 256) {
        int2 r = stage[sbase + j];
        int p = atomicAdd(&cur[r.x], 1);
        buf[p] = (unsigned int)r.y;
    }
    __syncthreads();
    for (int j = tid; j < ecnt; j += 256)
        edges[sbase + j] = buf[j];
    // fused dinv: deg = 1 + sum w over the node's CSR slice (in LDS)
    for (int l = tid; l < nn; l += 256) {
        int lo = ex[l];
        int h2 = ex[l + 1];
        float sm = 1.0f;
        for (int j = lo; j < h2; j++) sm += unpackw(buf[j]);
        dinv[n0 + l] = rsqrtf(sm);
    }
}

// ---------------- weight transpose + front-end init (fused) ----------------

__global__ void k_wt2(const float* __restrict__ Wa, const float* __restrict__ Wb,
                      f16* __restrict__ Wta, f16* __restrict__ Wtb,
                      int* __restrict__ gcur, unsigned int* __restrict__ edges) {
    int t = threadIdx.x;
    if (blockIdx.x == 2) {
        if (t < NCBK) gcur[t] = 0;
        // 8 zero sentinels past the last bucket region (uint4 tail overread)
        if (t >= 248) edges[(size_t)NCBK * BUFCAP + (t - 248)] = 0u;
        return;
    }
    const float* W = blockIdx.x ? Wb : Wa;
    f16* Wt = blockIdx.x ? Wtb : Wta;
#pragma unroll
    for (int it = 0; it < 64; it++) {
        int idx = t + it * 256;
        int k = idx >> 7, n = idx & 127;
        Wt[n * 128 + k] = (f16)W[idx];
    }
}

// ---------------- fp16 MFMA GEMM (layer 1, fused fp32->fp16 A conversion) ----------------

#define LDK 136

__launch_bounds__(256, 2)
__global__ void k_gemmf(const float* __restrict__ A, const f16* __restrict__ Wt,
                        const float* __restrict__ dinv, f16* __restrict__ H, int nrows) {
    __shared__ f16 Ws[128 * LDK];
    int tid = threadIdx.x;
    int r0 = blockIdx.x * 128;
    int wave = tid >> 6;
    int lane = tid & 63;
    int lrow = lane & 15;
    int quad = lane >> 4;

    f16x8 a[2][4];
#pragma unroll
    for (int mt = 0; mt < 2; mt++) {
        int row = r0 + wave * 32 + mt * 16 + lrow;
#pragma unroll
        for (int kc = 0; kc < 4; kc++) {
            if (row < nrows) {
                float4 lo = *(const float4*)&A[(size_t)row * F + kc * 32 + quad * 8];
                float4 hi = *(const float4*)&A[(size_t)row * F + kc * 32 + quad * 8 + 4];
                f16x8 f;
                f[0] = (f16)lo.x; f[1] = (f16)lo.y; f[2] = (f16)lo.z; f[3] = (f16)lo.w;
                f[4] = (f16)hi.x; f[5] = (f16)hi.y; f[6] = (f16)hi.z; f[7] = (f16)hi.w;
                a[mt][kc] = f;
            } else {
                a[mt][kc] = (f16x8){};
            }
        }
    }
#pragma unroll
    for (int it = 0; it < 8; it++) {
        int c = tid + it * 256;
        int rw = c >> 4;
        int off = (c & 15) * 8;
        *(f16x8*)&Ws[rw * LDK + off] = *(const f16x8*)&Wt[rw * 128 + off];
    }
    __syncthreads();

    f32x4 acc[2][8] = {};
#pragma unroll
    for (int kc = 0; kc < 4; kc++) {
        f16x8 b[8];
#pragma unroll
        for (int nt = 0; nt < 8; nt++)
            b[nt] = *(const f16x8*)&Ws[(nt * 16 + lrow) * LDK + kc * 32 + quad * 8];
#pragma unroll
        for (int nt = 0; nt < 8; nt++) {
            acc[0][nt] = __builtin_amdgcn_mfma_f32_16x16x32_f16(a[0][kc], b[nt], acc[0][nt], 0, 0, 0);
            acc[1][nt] = __builtin_amdgcn_mfma_f32_16x16x32_f16(a[1][kc], b[nt], acc[1][nt], 0, 0, 0);
        }
    }
    __syncthreads();
#pragma unroll
    for (int mt = 0; mt < 2; mt++) {
#pragma unroll
        for (int r = 0; r < 4; r++) {
            int lr = wave * 32 + mt * 16 + quad * 4 + r;
            int grow = r0 + lr;
            float dv = (grow < nrows) ? dinv[grow] : 0.f;
#pragma unroll
            for (int nt = 0; nt < 8; nt++)
                Ws[lr * 132 + nt * 16 + lrow] = (f16)(acc[mt][nt][r] * dv);
        }
    }
    __syncthreads();
#pragma unroll
    for (int it = 0; it < 8; it++) {
        int c = it * 256 + tid;
        int rw = c >> 4;
        int col = (c & 15) * 8;
        int grow = r0 + rw;
        if (grow < nrows)
            *(f16x8*)&H[(size_t)grow * F + col] = *(const f16x8*)&Ws[rw * 132 + col];
    }
}

// ---------------- R19 (final): fused aggregation + GEMM ----------------
// One block = 128 nodes. Phase 1: R16 quarter-wave gather per node, relu'd
// rows written to a 34 KB LDS tile (the GEMM A-tile) instead of global AB16 —
// kills the 25.6 MB write + 25.6 MB read round-trip per layer. Phase 2: a-frags
// to registers; the SAME LDS buffer is then re-staged with Wt (keeps LDS at
// 34 KB -> 4 blocks/CU, preserving gather-phase occupancy); MFMA; dinv
// epilogue; coalesced store. Hin/Hout ping-pong.
// [R20: barrier-free + B-from-global = +5.5 µs (VMEM queue). R21: single
//  barrier + B in own LDS buf = +13 µs (occupancy halved). This 5-barrier
//  34 KB shape is the measured optimum — queue-cap roofline.]
__launch_bounds__(256, 4)
__global__ void k_agg_gemm(const f16* __restrict__ Hin, const int2* __restrict__ row2,
                           const unsigned int* __restrict__ edges,
                           const float* __restrict__ dinv, const float* __restrict__ bias,
                           const f16* __restrict__ Wt, f16* __restrict__ Hout, int nrows) {
    __shared__ f16 S[128 * LDK];   // phase1: A-tile; then Ws; then epilogue buffer
    int tid = threadIdx.x;
    int r0 = blockIdx.x * 128;
    int wave = tid >> 6;
    int lane = tid & 63;
    int sub = lane & 15;
    int quad = lane >> 4;

    // ---- phase 1: aggregate this block's 128 nodes into S ----
    float4 b0 = *(const float4*)&bias[sub * 8];
    float4 b1 = *(const float4*)&bias[sub * 8 + 4];
    float bb[8] = {b0.x, b0.y, b0.z, b0.w, b1.x, b1.y, b1.z, b1.w};
    for (int it = 0; it < 8; it++) {
        int l = wave * 32 + it * 4 + quad;     // local row 0..127
        int node = r0 + l;
        f16x8 o = (f16x8){};
        if (node < nrows) {
            int2 rr = row2[node];
            int beg = rr.x, end = rr.y;
            float acc0[8] = {}, acc1[8] = {}, acc2[8] = {}, acc3[8] = {};
            for (int t = (beg & ~3); t < end; t += 8) {
                uint4 ea = *(const uint4*)&edges[t];
                uint4 eb = *(const uint4*)&edges[t + 4];
                unsigned int e[8] = {ea.x, ea.y, ea.z, ea.w, eb.x, eb.y, eb.z, eb.w};
                float w[8];
                unsigned int srcw[8];
#pragma unroll
                for (int k = 0; k < 8; k++) {
                    bool live = (t + k >= beg) && (t + k < end);
                    w[k] = live ? unpackw(e[k]) : 0.f;
                    srcw[k] = (t + k < end) ? e[k] : ea.x;
                }
                f16x8 v[8];
#pragma unroll
                for (int k = 0; k < 8; k++)
                    v[k] = *(const f16x8*)&Hin[(size_t)(srcw[k] >> 15) * F + sub * 8];
#pragma unroll
                for (int j = 0; j < 8; j++) {
                    acc0[j] = fmaf(w[0], (float)v[0][j], acc0[j]);
                    acc1[j] = fmaf(w[1], (float)v[1][j], acc1[j]);
                    acc2[j] = fmaf(w[2], (float)v[2][j], acc2[j]);
                    acc3[j] = fmaf(w[3], (float)v[3][j], acc3[j]);
                    acc0[j] = fmaf(w[4], (float)v[4][j], acc0[j]);
                    acc1[j] = fmaf(w[5], (float)v[5][j], acc1[j]);
                    acc2[j] = fmaf(w[6], (float)v[6][j], acc2[j]);
                    acc3[j] = fmaf(w[7], (float)v[7][j], acc3[j]);
                }
            }
            float dd = dinv[node];
            f16x8 h = *(const f16x8*)&Hin[(size_t)node * F + sub * 8];
#pragma unroll
            for (int j = 0; j < 8; j++) {
                float a = acc0[j] + acc1[j] + acc2[j] + acc3[j] + (float)h[j];
                o[j] = (f16)fmaxf(fmaf(dd, a, bb[j]), 0.f);
            }
        }
        *(f16x8*)&S[l * LDK + sub * 8] = o;
    }
    __syncthreads();

    // ---- phase 2: a-frags from S (rows stride LDK: 2-way bank alias, free) ----
    f16x8 a[2][4];
#pragma unroll
    for (int mt = 0; mt < 2; mt++) {
        int l = wave * 32 + mt * 16 + sub;
#pragma unroll
        for (int kc = 0; kc < 4; kc++)
            a[mt][kc] = *(const f16x8*)&S[l * LDK + kc * 32 + quad * 8];
    }
    __syncthreads();
    // ---- re-stage S with Wt ----
#pragma unroll
    for (int it = 0; it < 8; it++) {
        int c = tid + it * 256;
        int rw = c >> 4;
        int off = (c & 15) * 8;
        *(f16x8*)&S[rw * LDK + off] = *(const f16x8*)&Wt[rw * 128 + off];
    }
    __syncthreads();

    f32x4 acc[2][8] = {};
#pragma unroll
    for (int kc = 0; kc < 4; kc++) {
        f16x8 b[8];
#pragma unroll
        for (int nt = 0; nt < 8; nt++)
            b[nt] = *(const f16x8*)&S[(nt * 16 + sub) * LDK + kc * 32 + quad * 8];
#pragma unroll
        for (int nt = 0; nt < 8; nt++) {
            acc[0][nt] = __builtin_amdgcn_mfma_f32_16x16x32_f16(a[0][kc], b[nt], acc[0][nt], 0, 0, 0);
            acc[1][nt] = __builtin_amdgcn_mfma_f32_16x16x32_f16(a[1][kc], b[nt], acc[1][nt], 0, 0, 0);
        }
    }
    __syncthreads();
#pragma unroll
    for (int mt = 0; mt < 2; mt++) {
#pragma unroll
        for (int r = 0; r < 4; r++) {
            int lr = wave * 32 + mt * 16 + quad * 4 + r;
            int grow = r0 + lr;
            float dv = (grow < nrows) ? dinv[grow] : 0.f;
#pragma unroll
            for (int nt = 0; nt < 8; nt++)
                S[lr * 132 + nt * 16 + sub] = (f16)(acc[mt][nt][r] * dv);
        }
    }
    __syncthreads();
#pragma unroll
    for (int it = 0; it < 8; it++) {
        int c = it * 256 + tid;
        int rw = c >> 4;
        int col = (c & 15) * 8;
        int grow = r0 + rw;
        if (grow < nrows)
            *(f16x8*)&Hout[(size_t)grow * F + col] = *(const f16x8*)&S[rw * 132 + col];
    }
}

// agg3 fused with final dot: s'[node] = dinv[node] * ( relu(agg3) . Wfin )
__launch_bounds__(256)
__global__ void k_agg_dot(const f16* __restrict__ H16, const int2* __restrict__ row2,
                          const unsigned int* __restrict__ edges,
                          const float* __restrict__ dinv, const float* __restrict__ bias,
                          const float* __restrict__ Wf, float* __restrict__ sout, int n) {
    int node = blockIdx.x * 16 + (threadIdx.x >> 4);
    if (node >= n) return;
    int sub = threadIdx.x & 15;
    int2 rr = row2[node];
    int beg = rr.x, end = rr.y;
    float acc0[8] = {}, acc1[8] = {}, acc2[8] = {}, acc3[8] = {};
    for (int t = (beg & ~3); t < end; t += 8) {
        uint4 ea = *(const uint4*)&edges[t];
        uint4 eb = *(const uint4*)&edges[t + 4];
        unsigned int e[8] = {ea.x, ea.y, ea.z, ea.w, eb.x, eb.y, eb.z, eb.w};
        float w[8];
        unsigned int srcw[8];
#pragma unroll
        for (int k = 0; k < 8; k++) {
            bool live = (t + k >= beg) && (t + k < end);
            w[k] = live ? unpackw(e[k]) : 0.f;
            srcw[k] = (t + k < end) ? e[k] : ea.x;
        }
        f16x8 v[8];
#pragma unroll
        for (int k = 0; k < 8; k++)
            v[k] = *(const f16x8*)&H16[(size_t)(srcw[k] >> 15) * F + sub * 8];
#pragma unroll
        for (int j = 0; j < 8; j++) {
            acc0[j] = fmaf(w[0], (float)v[0][j], acc0[j]);
            acc1[j] = fmaf(w[1], (float)v[1][j], acc1[j]);
            acc2[j] = fmaf(w[2], (float)v[2][j], acc2[j]);
            acc3[j] = fmaf(w[3], (float)v[3][j], acc3[j]);
            acc0[j] = fmaf(w[4], (float)v[4][j], acc0[j]);
            acc1[j] = fmaf(w[5], (float)v[5][j], acc1[j]);
            acc2[j] = fmaf(w[6], (float)v[6][j], acc2[j]);
            acc3[j] = fmaf(w[7], (float)v[7][j], acc3[j]);
        }
    }
    float dd = dinv[node];
    f16x8 h = *(const f16x8*)&H16[(size_t)node * F + sub * 8];
    float4 b0 = *(const float4*)&bias[sub * 8];
    float4 b1 = *(const float4*)&bias[sub * 8 + 4];
    float bb[8] = {b0.x, b0.y, b0.z, b0.w, b1.x, b1.y, b1.z, b1.w};
    float4 w0v = *(const float4*)&Wf[sub * 8];
    float4 w1v = *(const float4*)&Wf[sub * 8 + 4];
    float ww[8] = {w0v.x, w0v.y, w0v.z, w0v.w, w1v.x, w1v.y, w1v.z, w1v.w};
    float p = 0.f;
#pragma unroll
    for (int j = 0; j < 8; j++) {
        float a = acc0[j] + acc1[j] + acc2[j] + acc3[j] + (float)h[j];
        p += fmaxf(fmaf(dd, a, bb[j]), 0.f) * ww[j];
    }
    p += __shfl_xor(p, 8, 64);
    p += __shfl_xor(p, 4, 64);
    p += __shfl_xor(p, 2, 64);
    p += __shfl_xor(p, 1, 64);
    if (sub == 0) sout[node] = dd * p;
}

__global__ void k_aggs(const float* __restrict__ s, const int2* __restrict__ row2,
                       const unsigned int* __restrict__ edges,
                       const float* __restrict__ dinv, const float* __restrict__ bf,
                       float* __restrict__ out, int n) {
    int i = blockIdx.x * blockDim.x + threadIdx.x;
    if (i >= n) return;
    float dd = dinv[i];
    float ae = s[i];
    int2 rr = row2[i];
    for (int j = rr.x; j < rr.y; j++) {
        unsigned int p = edges[j];
        ae = fmaf(unpackw(p), s[p >> 15], ae);
    }
    out[i] = fmaf(dd, ae, bf[0]);
}

// ---------------- host launch ----------------

extern "C" void kernel_launch(void* const* d_in, const int* in_sizes, int n_in,
                              void* d_out, int out_size, void* d_ws, size_t ws_size,
                              hipStream_t stream) {
    const float* x    = (const float*)d_in[0];
    const int*   ei   = (const int*)d_in[1];
    const float* ew   = (const float*)d_in[2];
    const float* Win  = (const float*)d_in[3];
    const float* bin  = (const float*)d_in[4];
    const float* Wmid = (const float*)d_in[5];
    const float* bmid = (const float*)d_in[6];
    const float* Wfin = (const float*)d_in[7];
    const float* bfin = (const float*)d_in[8];
    float* out = (float*)d_out;

    char* ws = (char*)d_ws;
    size_t off = 0;
    auto alloc = [&](size_t bytes) -> char* {
        char* p = ws + off;
        off = (off + bytes + 255) & ~(size_t)255;
        return p;
    };
    float* dinv  = (float*)alloc((size_t)N_NODES * 4);
    int2*  row2  = (int2*)alloc((size_t)N_NODES * 8);
    unsigned int* edges = (unsigned int*)alloc(((size_t)NCBK * BUFCAP + 8) * 4);  // padded buckets + sentinels
    int*   gcur  = (int*)alloc(256 * 4);
    f16*   wtin  = (f16*)alloc(128 * 128 * 2);
    f16*   wtmid = (f16*)alloc(128 * 128 * 2);
    f16*   Ha    = (f16*)alloc((size_t)N_NODES * F * 2);   // ping
    f16*   Hb    = (f16*)alloc((size_t)N_NODES * F * 2);   // pong
    // stage aliased into Ha (consumed by binB before gemmf writes Ha):
    // NCBK * BUFCAP * 8 B = 16.06 MB <= 25.6 MB
    int2* stage = (int2*)Ha;
    float* sbuf = (float*)Hb;  // aliased: Hb consumed by fused2 before agg_dot writes

    dim3 b256(256);
    int gN = (N_NODES + 255) / 256;
    int gW = (N_NODES + 15) / 16;
    int gG = (N_NODES + 127) / 128;
    int gA = (N_EDGES + CHUNK - 1) / CHUNK;   // 391

    hipLaunchKernelGGL(k_wt2, dim3(3), b256, 0, stream, Win, Wmid, wtin, wtmid, gcur, edges);
    hipLaunchKernelGGL(k_binA, dim3(gA), b256, 0, stream, ei, ew, gcur, stage, N_EDGES);
    hipLaunchKernelGGL(k_binB, dim3(NCBK), b256, 0, stream, stage, gcur, edges, row2, dinv);

    hipLaunchKernelGGL(k_gemmf, dim3(gG), b256, 0, stream, x, wtin, dinv, Ha, N_NODES);
    hipLaunchKernelGGL(k_agg_gemm, dim3(gG), b256, 0, stream, Ha, row2, edges, dinv, bin, wtmid, Hb, N_NODES);
    hipLaunchKernelGGL(k_agg_gemm, dim3(gG), b256, 0, stream, Hb, row2, edges, dinv, bmid, wtmid, Ha, N_NODES);
    hipLaunchKernelGGL(k_agg_dot, dim3(gW), b256, 0, stream, Ha, row2, edges, dinv, bmid, Wfin, sbuf, N_NODES);
    hipLaunchKernelGGL(k_aggs, dim3(gN), b256, 0, stream, sbuf, row2, edges, dinv, bfin, out, N_NODES);
}